// Round 2
// baseline (4190.981 us; speedup 1.0000x reference)
//
#include <hip/hip_runtime.h>

// DGCNN-style net, fused one-block-per-batch (B=1024, 256 thr), round 2.
// Key changes vs round 1:
//  - weights via wave-uniform indexing -> s_load into SGPRs; activations in VGPRs
//  - all LDS arrays XOR-quad-swizzled (conflict-free for lane-varying rows)
//  - LDS 53.1KB -> 3 blocks/CU; kNN (waves 0-1) || P-GEMM (waves 2-3)
//  - Q = P2 - P1 (second-half GEMM minus LDS-resident P)

#define NPT 100
#define KK  10

__device__ __forceinline__ float leaky(float v) { return fmaxf(v, 0.2f * v); }

// swizzled quad (16B) index helpers: quad q of row n -> physical quad
__device__ __forceinline__ int xcq(int n, int q) { return n * 24 + (q ^ (n & 7)); } // XC: 24 quads/row
__device__ __forceinline__ int pbq(int n, int q) { return n * 8  + (q ^ (n & 7)); } // PB rows: 8 quads/row
__device__ __forceinline__ int h2q(int n, int q) { return n * 32 + (q ^ (n & 7)); } // h2c: 32 quads/row

// ---------- xx[n] = sum_c x[n][c]^2 ----------
__device__ __forceinline__ void xx_phase(const float* XC, float* MISC, int tid, int qoff) {
  if (tid < NPT) {
    float a = 0.f;
    #pragma unroll
    for (int q = 0; q < 8; ++q) {
      float4 v = *(const float4*)&XC[xcq(tid, qoff + q) << 2];
      a = fmaf(v.x, v.x, fmaf(v.y, v.y, fmaf(v.z, v.z, fmaf(v.w, v.w, a))));
    }
    MISC[tid] = a;
  }
}

// ---------- kNN top-10 (waves 0-1, thread-per-n) ----------
__device__ __forceinline__ void knn_phase(const float* XC, const float* MISC,
                                          unsigned char* IDXB, int tid, int qoff) {
  if (tid >= NPT) return;
  const int n = tid;
  float xr[32];
  #pragma unroll
  for (int q = 0; q < 8; ++q) {
    float4 v = *(const float4*)&XC[xcq(n, qoff + q) << 2];
    xr[q*4+0] = v.x; xr[q*4+1] = v.y; xr[q*4+2] = v.z; xr[q*4+3] = v.w;
  }
  const float xxn = MISC[n];
  float bv[KK]; int bj[KK];
  #pragma unroll
  for (int k = 0; k < KK; ++k) { bv[k] = -3.4e38f; bj[k] = 0; }
  #pragma unroll 1
  for (int m = 0; m < NPT; ++m) {
    float p0 = 0.f, p1 = 0.f, p2 = 0.f, p3 = 0.f;
    #pragma unroll
    for (int q = 0; q < 8; ++q) {
      float4 v = *(const float4*)&XC[xcq(m, qoff + q) << 2];  // uniform addr -> broadcast
      p0 = fmaf(xr[q*4+0], v.x, p0);
      p1 = fmaf(xr[q*4+1], v.y, p1);
      p2 = fmaf(xr[q*4+2], v.z, p2);
      p3 = fmaf(xr[q*4+3], v.w, p3);
    }
    float d = 2.0f * ((p0 + p1) + (p2 + p3)) - xxn - MISC[m];
    if (d > bv[KK-1]) {            // strict >: earlier m wins ties (matches lax.top_k set)
      float cv = d; int ci = m;
      #pragma unroll
      for (int j = 0; j < KK; ++j) {
        bool sw = cv > bv[j];
        float tv = bv[j]; int ti = bj[j];
        bv[j] = sw ? cv : tv; bj[j] = sw ? ci : ti;
        cv = sw ? tv : cv;    ci = sw ? ti : ci;
      }
    }
  }
  #pragma unroll
  for (int k = 0; k < KK; ++k) IDXB[n*KK + k] = (unsigned char)bj[k];
}

// ---------- P[j][o] = sum_c Wa[o][c] * x[j][c]   (waves 2-3) ----------
__device__ __forceinline__ void pgemm(const float* XC, float* PB,
                                      const float* __restrict__ Wa, int tid, int qoff) {
  int j = tid - 128;
  if (j < 0 || j >= NPT) return;
  float xr[32];
  #pragma unroll
  for (int q = 0; q < 8; ++q) {
    float4 v = *(const float4*)&XC[xcq(j, qoff + q) << 2];
    xr[q*4+0] = v.x; xr[q*4+1] = v.y; xr[q*4+2] = v.z; xr[q*4+3] = v.w;
  }
  #pragma unroll
  for (int og = 0; og < 4; ++og) {
    float t[8] = {0,0,0,0,0,0,0,0};
    #pragma unroll
    for (int c = 0; c < 32; ++c) {
      #pragma unroll
      for (int oi = 0; oi < 8; ++oi)
        t[oi] = fmaf(Wa[(og*8 + oi)*64 + c], xr[c], t[oi]);   // uniform -> s_load
    }
    *(float4*)&PB[pbq(j, og*2 + 0) << 2] = make_float4(t[0], t[1], t[2], t[3]);
    *(float4*)&PB[pbq(j, og*2 + 1) << 2] = make_float4(t[4], t[5], t[6], t[7]);
  }
}

// ---------- EdgeConv main (layers 1,2): E=leaky((P[j]+Q[n])*sa+ta); conv Wb; max_k ----------
__device__ __forceinline__ void ephase(float* XC, const float* PB, const unsigned char* IDXB,
                                       const float* __restrict__ Wa, const float* __restrict__ Wb,
                                       const float* __restrict__ sa, const float* __restrict__ ta,
                                       const float* __restrict__ sb, const float* __restrict__ tb,
                                       int tid, int qoff, int oq) {
  if (tid >= NPT) return;
  const int n = tid;
  float xr[32];
  #pragma unroll
  for (int q = 0; q < 8; ++q) {
    float4 v = *(const float4*)&XC[xcq(n, qoff + q) << 2];
    xr[q*4+0] = v.x; xr[q*4+1] = v.y; xr[q*4+2] = v.z; xr[q*4+3] = v.w;
  }
  // Q = P2 - P1  (P2: second weight half; P1: LDS-resident P row n)
  float qv[32];
  #pragma unroll
  for (int og = 0; og < 4; ++og) {
    float t[8] = {0,0,0,0,0,0,0,0};
    #pragma unroll
    for (int c = 0; c < 32; ++c) {
      #pragma unroll
      for (int oi = 0; oi < 8; ++oi)
        t[oi] = fmaf(Wa[(og*8 + oi)*64 + 32 + c], xr[c], t[oi]);
    }
    float4 a = *(const float4*)&PB[pbq(n, og*2 + 0) << 2];
    float4 b = *(const float4*)&PB[pbq(n, og*2 + 1) << 2];
    qv[og*8+0] = t[0] - a.x; qv[og*8+1] = t[1] - a.y;
    qv[og*8+2] = t[2] - a.z; qv[og*8+3] = t[3] - a.w;
    qv[og*8+4] = t[4] - b.x; qv[og*8+5] = t[5] - b.y;
    qv[og*8+6] = t[6] - b.z; qv[og*8+7] = t[7] - b.w;
  }
  float acc[32];
  #pragma unroll
  for (int o = 0; o < 32; ++o) acc[o] = -3.4e38f;
  #pragma unroll 1
  for (int k = 0; k < KK; ++k) {
    int j = IDXB[n*KK + k];
    float e[32];
    #pragma unroll
    for (int q = 0; q < 8; ++q) {
      float4 p = *(const float4*)&PB[pbq(j, q) << 2];
      e[q*4+0] = leaky(fmaf(p.x + qv[q*4+0], sa[q*4+0], ta[q*4+0]));
      e[q*4+1] = leaky(fmaf(p.y + qv[q*4+1], sa[q*4+1], ta[q*4+1]));
      e[q*4+2] = leaky(fmaf(p.z + qv[q*4+2], sa[q*4+2], ta[q*4+2]));
      e[q*4+3] = leaky(fmaf(p.w + qv[q*4+3], sa[q*4+3], ta[q*4+3]));
    }
    #pragma unroll
    for (int og = 0; og < 4; ++og) {
      float t[8] = {0,0,0,0,0,0,0,0};
      #pragma unroll
      for (int c = 0; c < 32; ++c) {
        #pragma unroll
        for (int oi = 0; oi < 8; ++oi)
          t[oi] = fmaf(Wb[(og*8 + oi)*32 + c], e[c], t[oi]);
      }
      #pragma unroll
      for (int oi = 0; oi < 8; ++oi)
        acc[og*8 + oi] = fmaxf(acc[og*8 + oi], t[oi]);
    }
  }
  #pragma unroll
  for (int q = 0; q < 8; ++q) {
    int o0 = q * 4;
    float4 v = make_float4(leaky(fmaf(acc[o0+0], sb[o0+0], tb[o0+0])),
                           leaky(fmaf(acc[o0+1], sb[o0+1], tb[o0+1])),
                           leaky(fmaf(acc[o0+2], sb[o0+2], tb[o0+2])),
                           leaky(fmaf(acc[o0+3], sb[o0+3], tb[o0+3])));
    *(float4*)&XC[xcq(n, oq + q) << 2] = v;
  }
}

// ---------- EdgeConv last (layer 3): x3 = leaky((max_k P[j] + Q)*s+t) ----------
__device__ __forceinline__ void econv3_final(float* XC, const float* PB, const unsigned char* IDXB,
                                             const float* __restrict__ Wa,
                                             const float* __restrict__ sa, const float* __restrict__ ta,
                                             int tid) {
  if (tid >= NPT) return;
  const int n = tid;
  float xr[32];
  #pragma unroll
  for (int q = 0; q < 8; ++q) {
    float4 v = *(const float4*)&XC[xcq(n, 8 + q) << 2];   // x2 at quads 8..16
    xr[q*4+0] = v.x; xr[q*4+1] = v.y; xr[q*4+2] = v.z; xr[q*4+3] = v.w;
  }
  float qv[32];
  #pragma unroll
  for (int og = 0; og < 4; ++og) {
    float t[8] = {0,0,0,0,0,0,0,0};
    #pragma unroll
    for (int c = 0; c < 32; ++c) {
      #pragma unroll
      for (int oi = 0; oi < 8; ++oi)
        t[oi] = fmaf(Wa[(og*8 + oi)*64 + 32 + c], xr[c], t[oi]);
    }
    float4 a = *(const float4*)&PB[pbq(n, og*2 + 0) << 2];
    float4 b = *(const float4*)&PB[pbq(n, og*2 + 1) << 2];
    qv[og*8+0] = t[0] - a.x; qv[og*8+1] = t[1] - a.y;
    qv[og*8+2] = t[2] - a.z; qv[og*8+3] = t[3] - a.w;
    qv[og*8+4] = t[4] - b.x; qv[og*8+5] = t[5] - b.y;
    qv[og*8+6] = t[6] - b.z; qv[og*8+7] = t[7] - b.w;
  }
  float vm[32];
  #pragma unroll
  for (int o = 0; o < 32; ++o) vm[o] = -3.4e38f;
  #pragma unroll 1
  for (int k = 0; k < KK; ++k) {
    int j = IDXB[n*KK + k];
    #pragma unroll
    for (int q = 0; q < 8; ++q) {
      float4 p = *(const float4*)&PB[pbq(j, q) << 2];
      vm[q*4+0] = fmaxf(vm[q*4+0], p.x);
      vm[q*4+1] = fmaxf(vm[q*4+1], p.y);
      vm[q*4+2] = fmaxf(vm[q*4+2], p.z);
      vm[q*4+3] = fmaxf(vm[q*4+3], p.w);
    }
  }
  #pragma unroll
  for (int q = 0; q < 8; ++q) {
    int o0 = q * 4;
    float4 v = make_float4(leaky(fmaf(vm[o0+0] + qv[o0+0], sa[o0+0], ta[o0+0])),
                           leaky(fmaf(vm[o0+1] + qv[o0+1], sa[o0+1], ta[o0+1])),
                           leaky(fmaf(vm[o0+2] + qv[o0+2], sa[o0+2], ta[o0+2])),
                           leaky(fmaf(vm[o0+3] + qv[o0+3], sa[o0+3], ta[o0+3])));
    *(float4*)&XC[xcq(n, 16 + q) << 2] = v;   // x3 at quads 16..24
  }
}

__global__ __launch_bounds__(256, 3) void dgcnn(
    const float* __restrict__ obs,
    const float* __restrict__ W0, const float* __restrict__ W1, const float* __restrict__ W2,
    const float* __restrict__ W3, const float* __restrict__ W4, const float* __restrict__ W5,
    const float* __restrict__ W6, const float* __restrict__ W7, const float* __restrict__ W8,
    const float* __restrict__ W9,
    const float* __restrict__ s0, const float* __restrict__ t0,
    const float* __restrict__ s1, const float* __restrict__ t1,
    const float* __restrict__ s2, const float* __restrict__ t2,
    const float* __restrict__ s3, const float* __restrict__ t3,
    const float* __restrict__ s4, const float* __restrict__ t4,
    const float* __restrict__ s5, const float* __restrict__ t5,
    const float* __restrict__ s6, const float* __restrict__ t6,
    const float* __restrict__ s7, const float* __restrict__ t7,
    const float* __restrict__ s8, const float* __restrict__ t8,
    float* __restrict__ out) {
  const int b = blockIdx.x;
  const int tid = threadIdx.x;

  __shared__ __align__(16) float XC[9600];   // [100][96] swizzled: x1|x2|x3 (x0 in x3 slot early)
  __shared__ __align__(16) float PB[3200];   // obs-stage -> P[100][32] -> g[512] -> h2c[25][128]
  __shared__ __align__(16) float MISC[228];  // [0..100) xx / W9-partials; [100..228) Rg
  __shared__ unsigned char IDXB[NPT * KK];

  // ================= stage obs (zero-padded [100][32], swizzled) =================
  for (int i = tid; i < 3200; i += 256) {
    int n = i >> 5, c = i & 31;
    float v = (c < 30) ? obs[(size_t)b * 3000 + n * 30 + c] : 0.f;
    PB[(pbq(n, c >> 2) << 2) | (c & 3)] = v;
  }
  __syncthreads();

  // ================= conv0: 30 -> 32, x0 -> XC quads 16..24 =================
  {
    int w = __builtin_amdgcn_readfirstlane(tid >> 6);
    int h = w >> 1;                    // waves 0-1: o 0..15; waves 2-3: o 16..31
    int n = tid & 127;
    if (n < NPT) {
      float xr[32];
      #pragma unroll
      for (int q = 0; q < 8; ++q) {
        float4 v = *(const float4*)&PB[pbq(n, q) << 2];
        xr[q*4+0] = v.x; xr[q*4+1] = v.y; xr[q*4+2] = v.z; xr[q*4+3] = v.w;
      }
      float o16[16];
      #pragma unroll
      for (int oi = 0; oi < 16; ++oi) {
        int o = h * 16 + oi;
        float a = 0.f;
        #pragma unroll
        for (int c = 0; c < 30; ++c) a = fmaf(W0[o*30 + c], xr[c], a);
        o16[oi] = leaky(fmaf(a, s0[o], t0[o]));
      }
      #pragma unroll
      for (int q = 0; q < 4; ++q)
        *(float4*)&XC[xcq(n, 16 + h*4 + q) << 2] =
            make_float4(o16[q*4+0], o16[q*4+1], o16[q*4+2], o16[q*4+3]);
    }
  }
  __syncthreads();

  // ================= edgeconv layer 1 (input x0 @ quads 16) =================
  xx_phase(XC, MISC, tid, 16);
  __syncthreads();
  if (tid < 128) knn_phase(XC, MISC, IDXB, tid, 16);
  else           pgemm(XC, PB, W1, tid, 16);
  __syncthreads();
  ephase(XC, PB, IDXB, W1, W2, s1, t1, s2, t2, tid, 16, 0);   // x1 -> quads 0..8
  __syncthreads();

  // ================= edgeconv layer 2 (input x1 @ quads 0) =================
  xx_phase(XC, MISC, tid, 0);
  __syncthreads();
  if (tid < 128) knn_phase(XC, MISC, IDXB, tid, 0);
  else           pgemm(XC, PB, W3, tid, 0);
  __syncthreads();
  ephase(XC, PB, IDXB, W3, W4, s3, t3, s4, t4, tid, 0, 8);    // x2 -> quads 8..16
  __syncthreads();

  // ================= edgeconv layer 3 (input x2 @ quads 8) =================
  xx_phase(XC, MISC, tid, 8);
  __syncthreads();
  if (tid < 128) knn_phase(XC, MISC, IDXB, tid, 8);
  else           pgemm(XC, PB, W5, tid, 8);
  __syncthreads();
  econv3_final(XC, PB, IDXB, W5, s5, t5, tid);                // x3 -> quads 16..24
  __syncthreads();

  // ================= W6 (512x96) + max over n -> g[512] in PB =================
  {
    int w    = __builtin_amdgcn_readfirstlane(tid >> 6);
    int lane = tid & 63;
    int wbase = w * 128;
    int n0 = lane;
    int n1 = 64 + lane;
    bool v1 = (n1 < NPT);
    int n1c = v1 ? n1 : 0;
    #pragma unroll 1
    for (int og = 0; og < 128; og += 8) {
      float ua[8] = {0,0,0,0,0,0,0,0};
      float ub[8] = {0,0,0,0,0,0,0,0};
      #pragma unroll
      for (int c4 = 0; c4 < 24; ++c4) {
        float4 xa = *(const float4*)&XC[xcq(n0,  c4) << 2];
        float4 xb = *(const float4*)&XC[xcq(n1c, c4) << 2];
        #pragma unroll
        for (int oi = 0; oi < 8; ++oi) {
          const float* wr = &W6[(wbase + og + oi)*96 + c4*4];
          ua[oi] = fmaf(wr[0], xa.x, fmaf(wr[1], xa.y, fmaf(wr[2], xa.z, fmaf(wr[3], xa.w, ua[oi]))));
          ub[oi] = fmaf(wr[0], xb.x, fmaf(wr[1], xb.y, fmaf(wr[2], xb.z, fmaf(wr[3], xb.w, ub[oi]))));
        }
      }
      #pragma unroll
      for (int oi = 0; oi < 8; ++oi) {
        float m = fmaxf(ua[oi], v1 ? ub[oi] : -3.4e38f);
        #pragma unroll
        for (int sh = 32; sh >= 1; sh >>= 1) m = fmaxf(m, __shfl_xor(m, sh, 64));
        if (lane == 0) {
          int o = wbase + og + oi;
          PB[o] = leaky(fmaf(m, s6[o], t6[o]));
        }
      }
    }
  }
  __syncthreads();

  // ================= Rg[o] = W7[o, :512] . g =================
  {
    int w    = __builtin_amdgcn_readfirstlane(tid >> 6);
    int lane = tid & 63;
    float4 g0 = *(const float4*)&PB[lane*8 + 0];
    float4 g1 = *(const float4*)&PB[lane*8 + 4];
    #pragma unroll 1
    for (int i = 0; i < 32; ++i) {
      int o = w * 32 + i;
      const float* wr = W7 + (size_t)o * 608 + lane * 8;
      float4 a0 = *(const float4*)&wr[0];
      float4 a1 = *(const float4*)&wr[4];
      float a = fmaf(a0.x, g0.x, fmaf(a0.y, g0.y, fmaf(a0.z, g0.z, fmaf(a0.w, g0.w,
                fmaf(a1.x, g1.x, fmaf(a1.y, g1.y, fmaf(a1.z, g1.z, fmaf(a1.w, g1.w, 0.f))))))));
      #pragma unroll
      for (int sh = 32; sh >= 1; sh >>= 1) a += __shfl_xor(a, sh, 64);
      if (lane == 0) MISC[100 + o] = a;
    }
  }
  __syncthreads();

  // ================= W7(96-part)+Rg -> h2c; W8 -> h3; W9 -> out  (n chunks of 25) =================
  for (int nb = 0; nb < NPT; nb += 25) {
    // W7 per-point part: wave w covers o in [32w, 32w+32), lanes = 25 points
    {
      int w     = __builtin_amdgcn_readfirstlane(tid >> 6);
      int lane  = tid & 63;
      int obase = w * 32;
      if (lane < 25) {
        int n = nb + lane;
        #pragma unroll 1
        for (int og = 0; og < 4; ++og) {
          float t[8] = {0,0,0,0,0,0,0,0};
          #pragma unroll
          for (int c4 = 0; c4 < 24; ++c4) {
            float4 x = *(const float4*)&XC[xcq(n, c4) << 2];
            #pragma unroll
            for (int oi = 0; oi < 8; ++oi) {
              const float* wr = &W7[(size_t)(obase + og*8 + oi)*608 + 512 + c4*4];
              t[oi] = fmaf(wr[0], x.x, fmaf(wr[1], x.y, fmaf(wr[2], x.z, fmaf(wr[3], x.w, t[oi]))));
            }
          }
          float hv[8];
          #pragma unroll
          for (int oi = 0; oi < 8; ++oi) {
            int o = obase + og*8 + oi;
            hv[oi] = leaky(fmaf(MISC[100 + o] + t[oi], s7[o], t7[o]));
          }
          *(float4*)&PB[h2q(lane, obase/4 + og*2 + 0) << 2] = make_float4(hv[0], hv[1], hv[2], hv[3]);
          *(float4*)&PB[h2q(lane, obase/4 + og*2 + 1) << 2] = make_float4(hv[4], hv[5], hv[6], hv[7]);
        }
      }
    }
    __syncthreads();
    // W8 (32x128) + leaky + W9 partial: wave w covers o8 in [8w, 8w+8)
    {
      int w    = __builtin_amdgcn_readfirstlane(tid >> 6);
      int lane = tid & 63;
      int o8   = w * 8;
      if (lane < 25) {
        float t[8] = {0,0,0,0,0,0,0,0};
        #pragma unroll
        for (int c4 = 0; c4 < 32; ++c4) {
          float4 hv = *(const float4*)&PB[h2q(lane, c4) << 2];
          #pragma unroll
          for (int oi = 0; oi < 8; ++oi) {
            const float* wr = &W8[(o8 + oi)*128 + c4*4];
            t[oi] = fmaf(wr[0], hv.x, fmaf(wr[1], hv.y, fmaf(wr[2], hv.z, fmaf(wr[3], hv.w, t[oi]))));
          }
        }
        float pp = 0.f;
        #pragma unroll
        for (int oi = 0; oi < 8; ++oi) {
          int o = o8 + oi;
          float h3 = leaky(fmaf(t[oi], s8[o], t8[o]));
          pp = fmaf(W9[o], h3, pp);
        }
        MISC[w*25 + lane] = pp;
      }
    }
    __syncthreads();
    if (tid < 25)
      out[(size_t)b*100 + nb + tid] = MISC[tid] + MISC[25 + tid] + MISC[50 + tid] + MISC[75 + tid];
    __syncthreads();
  }
}

extern "C" void kernel_launch(void* const* d_in, const int* in_sizes, int n_in,
                              void* d_out, int out_size, void* d_ws, size_t ws_size,
                              hipStream_t stream) {
  (void)n_in; (void)out_size; (void)d_ws; (void)ws_size;
  const float* obs = (const float*)d_in[0];
  const float* W[10];
  for (int i = 0; i < 10; ++i) W[i] = (const float*)d_in[1 + i];
  const float* s[9]; const float* t[9];
  for (int i = 0; i < 9; ++i) {
    s[i] = (const float*)d_in[11 + 2*i];
    t[i] = (const float*)d_in[12 + 2*i];
  }
  const int B = in_sizes[0] / 3000;
  dgcnn<<<B, 256, 0, stream>>>(obs,
      W[0], W[1], W[2], W[3], W[4], W[5], W[6], W[7], W[8], W[9],
      s[0], t[0], s[1], t[1], s[2], t[2], s[3], t[3], s[4], t[4],
      s[5], t[5], s[6], t[6], s[7], t[7], s[8], t[8],
      (float*)d_out);
}

// Round 3
// 716.753 us; speedup vs baseline: 5.8472x; 5.8472x over previous
//
#include <hip/hip_runtime.h>

#define NPT 100
#define KK 10

typedef __attribute__((ext_vector_type(8))) short short8;
typedef __attribute__((ext_vector_type(4))) float float4v;

__device__ __forceinline__ float leaky(float v){ return fmaxf(v, 0.2f*v); }
__device__ __forceinline__ unsigned short bf16r(float x){
  unsigned u = __float_as_uint(x);
  return (unsigned short)((u + 0x7FFFu + ((u>>16)&1u)) >> 16);
}
__device__ __forceinline__ float bf2f(unsigned short h){ return __uint_as_float(((unsigned)h)<<16); }

// d_ws layout. float offsets:
#define WV(w) (1024*(w))        // 9 folded 32x32 fp32 mats: W0f,Wp1,Wq1,W2f,Wp3,Wq3,W4f,Wp5,Wq5
#define W7G_OFF 9216            // W7 g-part folded fp32 [128][512]
// byte offsets:
#define W6B_OFF   299008        // W6 folded bf16 [512][288]  (K-blocks: 0-2 hi,3-5 hi,6-8 lo)
#define W796B_OFF 593920        // W7 96-part folded bf16 [128][288]
#define W8B_OFF   667648        // W8 folded bf16 [32][384]   (0-3 hi,4-7 hi,8-11 lo)

struct PrepP {
  const float* W[9];
  const float* s[9];
  float* ws;
};

__global__ __launch_bounds__(256) void prep_kernel(PrepP p){
  int gid = blockIdx.x*256 + threadIdx.x;
  int gs = gridDim.x*256;
  float* ws = p.ws;
  unsigned short* w6b  = (unsigned short*)((char*)ws + W6B_OFF);
  unsigned short* w796 = (unsigned short*)((char*)ws + W796B_OFF);
  unsigned short* w8b  = (unsigned short*)((char*)ws + W8B_OFF);
  // seg0: 9 folded vector mats [32][32]
  for(int i = gid; i < 9216; i += gs){
    int w = i >> 10, r = i & 1023, o = r >> 5, c = r & 31;
    float v = 0.f;
    switch(w){
      case 0: v = (c < 30) ? p.s[0][o]*p.W[0][o*30 + c] : 0.f; break;
      case 1: v = p.s[1][o]*p.W[1][o*64 + c]; break;
      case 2: v = p.s[1][o]*(p.W[1][o*64 + 32 + c] - p.W[1][o*64 + c]); break;
      case 3: v = p.s[2][o]*p.W[2][o*32 + c]; break;
      case 4: v = p.s[3][o]*p.W[3][o*64 + c]; break;
      case 5: v = p.s[3][o]*(p.W[3][o*64 + 32 + c] - p.W[3][o*64 + c]); break;
      case 6: v = p.s[4][o]*p.W[4][o*32 + c]; break;
      case 7: v = p.s[5][o]*p.W[5][o*64 + c]; break;
      case 8: v = p.s[5][o]*(p.W[5][o*64 + 32 + c] - p.W[5][o*64 + c]); break;
    }
    ws[i] = v;
  }
  // seg1: W7 g-part fp32 folded [128][512]
  for(int i = gid; i < 65536; i += gs){
    int o = i >> 9, c = i & 511;
    ws[W7G_OFF + i] = p.s[7][o]*p.W[7][o*608 + c];
  }
  // seg2: W6 bf16 [512][288]
  for(int i = gid; i < 147456; i += gs){
    int o = i/288, cc = i - o*288, kb = cc >> 5, k = cc & 31;
    int sc = (kb % 3)*32 + k;
    float w = p.s[6][o]*p.W[6][o*96 + sc];
    unsigned short h = bf16r(w);
    w6b[i] = (kb < 6) ? h : bf16r(w - bf2f(h));
  }
  // seg3: W7 96-part bf16 [128][288]
  for(int i = gid; i < 36864; i += gs){
    int o = i/288, cc = i - o*288, kb = cc >> 5, k = cc & 31;
    int sc = 512 + (kb % 3)*32 + k;
    float w = p.s[7][o]*p.W[7][o*608 + sc];
    unsigned short h = bf16r(w);
    w796[i] = (kb < 6) ? h : bf16r(w - bf2f(h));
  }
  // seg4: W8 bf16 [32][384]
  for(int i = gid; i < 12288; i += gs){
    int o = i/384, cc = i - o*384, kb = cc >> 5, k = cc & 31;
    int sc = (kb & 3)*32 + k;
    float w = p.s[8][o]*p.W[8][o*128 + sc];
    unsigned short h = bf16r(w);
    w8b[i] = (kb < 8) ? h : bf16r(w - bf2f(h));
  }
}

__device__ __forceinline__ void load32(const float* src, float* xr){
  #pragma unroll
  for(int q = 0; q < 8; ++q){
    float4v v = *(const float4v*)&src[q*4];
    xr[q*4+0] = v.x; xr[q*4+1] = v.y; xr[q*4+2] = v.z; xr[q*4+3] = v.w;
  }
}
__device__ __forceinline__ float dot32(const float* wrow, const float* xr){
  float a0 = 0.f, a1 = 0.f, a2 = 0.f, a3 = 0.f;
  #pragma unroll
  for(int q = 0; q < 8; ++q){
    float4v w = *(const float4v*)&wrow[q*4];
    a0 = fmaf(w.x, xr[q*4+0], a0);
    a1 = fmaf(w.y, xr[q*4+1], a1);
    a2 = fmaf(w.z, xr[q*4+2], a2);
    a3 = fmaf(w.w, xr[q*4+3], a3);
  }
  return (a0+a1)+(a2+a3);
}
// build hi/lo bf16 fragments (8 elems) from 8 consecutive fp32
__device__ __forceinline__ void buildB(const float* src, short8* bh, short8* bl){
  float4v v0 = *(const float4v*)&src[0];
  float4v v1 = *(const float4v*)&src[4];
  float xv[8] = {v0.x, v0.y, v0.z, v0.w, v1.x, v1.y, v1.z, v1.w};
  short8 h, l;
  #pragma unroll
  for(int j = 0; j < 8; ++j){
    unsigned short hh = bf16r(xv[j]);
    h[j] = (short)hh;
    l[j] = (short)bf16r(xv[j] - bf2f(hh));
  }
  *bh = h; *bl = l;
}

// conv2 k-chunk of 2: E in regs, weights broadcast from LDS
__device__ __forceinline__ void conv2_chunk2(int n, int k0, int ob,
    const unsigned char* IDXB, const float* PREG, const float* qt,
    const float* WST, float* acc){
  float e0[32], e1[32];
  #pragma unroll
  for(int kk = 0; kk < 2; ++kk){
    float* e = kk ? e1 : e0;
    int j = IDXB[n*KK + k0 + kk];
    #pragma unroll
    for(int q = 0; q < 8; ++q){
      float4v pv = *(const float4v*)&PREG[j*36 + q*4];
      e[q*4+0] = leaky(pv.x + qt[q*4+0]);
      e[q*4+1] = leaky(pv.y + qt[q*4+1]);
      e[q*4+2] = leaky(pv.z + qt[q*4+2]);
      e[q*4+3] = leaky(pv.w + qt[q*4+3]);
    }
  }
  #pragma unroll
  for(int o = 0; o < 8; ++o){
    float d0a = 0.f, d0b = 0.f, d1a = 0.f, d1b = 0.f;
    #pragma unroll
    for(int q = 0; q < 8; ++q){
      float4v w = *(const float4v*)&WST[(ob + o)*32 + q*4];
      d0a = fmaf(w.x, e0[q*4+0], d0a); d0b = fmaf(w.y, e0[q*4+1], d0b);
      d0a = fmaf(w.z, e0[q*4+2], d0a); d0b = fmaf(w.w, e0[q*4+3], d0b);
      d1a = fmaf(w.x, e1[q*4+0], d1a); d1b = fmaf(w.y, e1[q*4+1], d1b);
      d1a = fmaf(w.z, e1[q*4+2], d1a); d1b = fmaf(w.w, e1[q*4+3], d1b);
    }
    acc[o] = fmaxf(acc[o], fmaxf(d0a + d0b, d1a + d1b));
  }
}

struct MainP {
  const float* obs;
  const float* W9;
  const float* t[9];
  const float* ws;
  float* out;
};

__global__ __launch_bounds__(256, 2) void dgcnn(MainP p){
  const int b = blockIdx.x;
  const int tid = threadIdx.x;
  const int lane = tid & 63, wv = tid >> 6;
  const int quad = lane >> 4, l15 = lane & 15;

  // LDS: 40000 + 14400 + 8192 + 400 + 128 + 1000 = 64120 B
  __shared__ __align__(16) float XBIG[10000];  // [100][100]: x1(0-31)|x2(32-63)|x3/x0/Q(64-95)|pad
  __shared__ __align__(16) float PREG[3600];   // obs stage -> P[100][36] -> h2[16][132]
  __shared__ __align__(16) float WST[2048];    // weight stage / g[512]+Rg[128]
  __shared__ __align__(16) float XX[100];
  __shared__ __align__(16) float TMP[32];
  __shared__ unsigned char IDXB[1000];

  const float* ws = p.ws;
  const unsigned short* w6b  = (const unsigned short*)((const char*)ws + W6B_OFF);
  const unsigned short* w796 = (const unsigned short*)((const char*)ws + W796B_OFF);
  const unsigned short* w8b  = (const unsigned short*)((const char*)ws + W8B_OFF);

  // ---- stage obs (zero-padded [100][36]) + W0f ----
  for(int i = tid; i < 3600; i += 256){
    int n = i/36, c = i - n*36;
    PREG[i] = (c < 30) ? p.obs[(size_t)b*3000 + n*30 + c] : 0.f;
  }
  for(int i = tid; i < 1024; i += 256) WST[i] = ws[WV(0) + i];
  __syncthreads();

  // ---- conv0 (vector fp32, folded s0) -> x0 at cols 64-95 ----
  if(tid < NPT){
    float xr[32]; load32(&PREG[tid*36], xr);
    #pragma unroll
    for(int ob = 0; ob < 8; ++ob){
      float4v y;
      #pragma unroll
      for(int oi = 0; oi < 4; ++oi){
        int o = ob*4 + oi;
        y[oi] = leaky(dot32(&WST[o*32], xr) + p.t[0][o]);
      }
      *(float4v*)&XBIG[tid*100 + 64 + ob*4] = y;
    }
  }
  __syncthreads();

  // ---- 3 edge layers ----
  const int XINs[3]  = {64, 0, 32};
  const int QOFFs[3] = {32, 64, 0};
  const int OUTs[3]  = {0, 32, 64};
  const int WPI[3]   = {1, 4, 7};

  for(int L = 0; L < 3; ++L){
    const int XIN = XINs[L], OUT = OUTs[L], QOFF = QOFFs[L];
    // stage Wp, Wq
    for(int i = tid; i < 1024; i += 256){
      WST[i]        = ws[WV(WPI[L])   + i];
      WST[1024 + i] = ws[WV(WPI[L]+1) + i];
    }
    __syncthreads();
    // xx
    if(tid < NPT){
      float xr[32]; load32(&XBIG[tid*100 + XIN], xr);
      float a = 0.f;
      #pragma unroll
      for(int c = 0; c < 32; ++c) a = fmaf(xr[c], xr[c], a);
      XX[tid] = a;
    }
    __syncthreads();
    // knn (waves 0-1) || P,Q GEMMs (waves 2-3)
    if(tid < 128){
      if(tid < NPT){
        const int n = tid;
        float xr[32]; load32(&XBIG[n*100 + XIN], xr);
        const float xxn = XX[n];
        float bv[KK]; int bj[KK];
        #pragma unroll
        for(int k = 0; k < KK; ++k){ bv[k] = -3.4e38f; bj[k] = 0; }
        #pragma unroll 1
        for(int m = 0; m < NPT; ++m){
          const float* xm = &XBIG[m*100 + XIN];
          float a0 = 0.f, a1 = 0.f, a2 = 0.f, a3 = 0.f;
          #pragma unroll
          for(int q = 0; q < 8; ++q){
            float4v v = *(const float4v*)&xm[q*4];
            a0 = fmaf(xr[q*4+0], v.x, a0);
            a1 = fmaf(xr[q*4+1], v.y, a1);
            a2 = fmaf(xr[q*4+2], v.z, a2);
            a3 = fmaf(xr[q*4+3], v.w, a3);
          }
          float d = 2.0f*((a0+a1)+(a2+a3)) - xxn - XX[m];
          if(d > bv[KK-1]){   // strict >: earlier m wins ties (matches lax.top_k)
            float cv = d; int ci = m;
            #pragma unroll
            for(int jj = 0; jj < KK; ++jj){
              bool sw = cv > bv[jj];
              float tv = bv[jj]; int ti = bj[jj];
              bv[jj] = sw ? cv : tv; bj[jj] = sw ? ci : ti;
              cv = sw ? tv : cv;    ci = sw ? ti : ci;
            }
          }
        }
        #pragma unroll
        for(int k = 0; k < KK; ++k) IDXB[n*KK + k] = (unsigned char)bj[k];
      }
    } else {
      int j = tid - 128;
      if(j < NPT){
        float xr[32]; load32(&XBIG[j*100 + XIN], xr);
        #pragma unroll 1
        for(int o = 0; o < 32; ++o) PREG[j*36 + o] = dot32(&WST[o*32], xr);
        if(L < 2){
          #pragma unroll 1
          for(int o = 0; o < 32; ++o) XBIG[j*100 + QOFF + o] = dot32(&WST[1024 + o*32], xr);
        }
      }
    }
    __syncthreads();

    if(L < 2){
      // stage conv weights (folded) + t-biases
      int wci = (L == 0) ? 3 : 6;
      for(int i = tid; i < 1024; i += 256) WST[i] = ws[WV(wci) + i];
      if(tid < 32){
        WST[1024 + tid] = p.t[1 + 2*L][tid];
        WST[1056 + tid] = p.t[2 + 2*L][tid];
      }
      __syncthreads();
      // conv2: thread = (n, o-octet); E regenerated per octet, weights LDS broadcast
      for(int it = tid; it < 400; it += 256){
        int n = it % 100, oct = it / 100, ob = oct*8;
        float qt[32];
        #pragma unroll
        for(int q = 0; q < 8; ++q){
          float4v qv = *(const float4v*)&XBIG[n*100 + QOFF + q*4];
          float4v tv = *(const float4v*)&WST[1024 + q*4];
          qt[q*4+0] = qv.x + tv.x; qt[q*4+1] = qv.y + tv.y;
          qt[q*4+2] = qv.z + tv.z; qt[q*4+3] = qv.w + tv.w;
        }
        float acc[8];
        #pragma unroll
        for(int o = 0; o < 8; ++o) acc[o] = -3.4e38f;
        conv2_chunk2(n, 0, ob, IDXB, PREG, qt, WST, acc);
        conv2_chunk2(n, 2, ob, IDXB, PREG, qt, WST, acc);
        conv2_chunk2(n, 4, ob, IDXB, PREG, qt, WST, acc);
        conv2_chunk2(n, 6, ob, IDXB, PREG, qt, WST, acc);
        conv2_chunk2(n, 8, ob, IDXB, PREG, qt, WST, acc);
        #pragma unroll
        for(int oh = 0; oh < 2; ++oh){
          float4v y;
          #pragma unroll
          for(int oi = 0; oi < 4; ++oi){
            int o = ob + oh*4 + oi;
            y[oi] = leaky(acc[oh*4 + oi] + WST[1056 + o]);
          }
          *(float4v*)&XBIG[n*100 + OUT + ob + oh*4] = y;
        }
      }
      __syncthreads();
    } else {
      // layer 3: x3 = leaky(max_k P[j] + Q + t5), Q computed in-reg
      if(tid < NPT){
        float xr[32]; load32(&XBIG[tid*100 + XIN], xr);
        float pm[32];
        #pragma unroll
        for(int o = 0; o < 32; ++o) pm[o] = -3.4e38f;
        #pragma unroll 1
        for(int k = 0; k < KK; ++k){
          int j = IDXB[tid*KK + k];
          #pragma unroll
          for(int q = 0; q < 8; ++q){
            float4v pv = *(const float4v*)&PREG[j*36 + q*4];
            pm[q*4+0] = fmaxf(pm[q*4+0], pv.x);
            pm[q*4+1] = fmaxf(pm[q*4+1], pv.y);
            pm[q*4+2] = fmaxf(pm[q*4+2], pv.z);
            pm[q*4+3] = fmaxf(pm[q*4+3], pv.w);
          }
        }
        #pragma unroll 1
        for(int o = 0; o < 32; ++o){
          float qv = dot32(&WST[1024 + o*32], xr);
          XBIG[tid*100 + OUT + o] = leaky(pm[o] + qv + p.t[5][o]);
        }
      }
      __syncthreads();
    }
  }

  // ---- W6 (512x96) via MFMA bf16x3 split, max over n in-register -> g ----
  {
    float4v gmax[8];
    #pragma unroll
    for(int i = 0; i < 8; ++i){ gmax[i][0] = -3.4e38f; gmax[i][1] = -3.4e38f; gmax[i][2] = -3.4e38f; gmax[i][3] = -3.4e38f; }
    #pragma unroll 1
    for(int nt = 0; nt < 7; ++nt){
      int row = nt*16 + l15; if(row > 99) row = 99;   // dup row: harmless under max
      short8 Bh[3], Bl[3];
      #pragma unroll
      for(int g = 0; g < 3; ++g) buildB(&XBIG[row*100 + g*32 + quad*8], &Bh[g], &Bl[g]);
      #pragma unroll 1
      for(int mt = 0; mt < 8; ++mt){
        int orow = (wv*8 + mt)*16 + l15;
        const unsigned short* ar = w6b + orow*288 + quad*8;
        float4v d = {0.f, 0.f, 0.f, 0.f};
        #pragma unroll
        for(int kb = 0; kb < 9; ++kb){
          short8 a = *(const short8*)(ar + kb*32);
          short8 bb = (kb < 3) ? Bh[kb] : ((kb < 6) ? Bl[kb-3] : Bh[kb-6]);
          d = __builtin_amdgcn_mfma_f32_16x16x32_bf16(a, bb, d, 0, 0, 0);
        }
        #pragma unroll
        for(int r = 0; r < 4; ++r) gmax[mt][r] = fmaxf(gmax[mt][r], d[r]);
      }
    }
    #pragma unroll 1
    for(int mt = 0; mt < 8; ++mt){
      float4v m = gmax[mt];
      #pragma unroll
      for(int bit = 1; bit < 16; bit <<= 1){
        m[0] = fmaxf(m[0], __shfl_xor(m[0], bit, 64));
        m[1] = fmaxf(m[1], __shfl_xor(m[1], bit, 64));
        m[2] = fmaxf(m[2], __shfl_xor(m[2], bit, 64));
        m[3] = fmaxf(m[3], __shfl_xor(m[3], bit, 64));
      }
      if(l15 == 0){
        #pragma unroll
        for(int r = 0; r < 4; ++r){
          int o = (wv*8 + mt)*16 + quad*4 + r;
          WST[o] = leaky(m[r] + p.t[6][o]);   // g[512] at WST[0..512)
        }
      }
    }
  }
  __syncthreads();

  // ---- Rg[o] = W7g . g (vector fp32) ----
  if(tid < 128){
    const float* wr = &ws[W7G_OFF + tid*512];
    float a0 = 0.f, a1 = 0.f, a2 = 0.f, a3 = 0.f;
    #pragma unroll 4
    for(int c4 = 0; c4 < 128; ++c4){
      float4v w = *(const float4v*)&wr[c4*4];
      float4v g = *(const float4v*)&WST[c4*4];
      a0 = fmaf(w.x, g.x, a0); a1 = fmaf(w.y, g.y, a1);
      a2 = fmaf(w.z, g.z, a2); a3 = fmaf(w.w, g.w, a3);
    }
    WST[512 + tid] = (a0+a1)+(a2+a3);
  }
  __syncthreads();

  // ---- tail: per 16-point chunk: W7(96-part) MFMA -> h2; W8 MFMA; W9 reduce ----
  float* H2 = PREG;   // [16][132]
  #pragma unroll 1
  for(int nc = 0; nc < 7; ++nc){
    int n0 = nc*16;
    int row = n0 + l15; if(row > 99) row = 99;
    short8 Bh[3], Bl[3];
    #pragma unroll
    for(int g = 0; g < 3; ++g) buildB(&XBIG[row*100 + g*32 + quad*8], &Bh[g], &Bl[g]);
    #pragma unroll 1
    for(int mm = 0; mm < 2; ++mm){
      int Mt = wv*2 + mm;
      const unsigned short* ar = w796 + (Mt*16 + l15)*288 + quad*8;
      float4v d = {0.f, 0.f, 0.f, 0.f};
      #pragma unroll
      for(int kb = 0; kb < 9; ++kb){
        short8 a = *(const short8*)(ar + kb*32);
        short8 bb = (kb < 3) ? Bh[kb] : ((kb < 6) ? Bl[kb-3] : Bh[kb-6]);
        d = __builtin_amdgcn_mfma_f32_16x16x32_bf16(a, bb, d, 0, 0, 0);
      }
      float4v y;
      #pragma unroll
      for(int r = 0; r < 4; ++r){
        int ch = Mt*16 + quad*4 + r;
        y[r] = leaky(d[r] + WST[512 + ch] + p.t[7][ch]);
      }
      *(float4v*)&H2[l15*132 + Mt*16 + quad*4] = y;
    }
    __syncthreads();
    if(wv < 2){
      short8 Ch[4], Cl[4];
      #pragma unroll
      for(int g = 0; g < 4; ++g) buildB(&H2[l15*132 + g*32 + quad*8], &Ch[g], &Cl[g]);
      const unsigned short* ar = w8b + (wv*16 + l15)*384 + quad*8;
      float4v d = {0.f, 0.f, 0.f, 0.f};
      #pragma unroll
      for(int kb = 0; kb < 12; ++kb){
        short8 a = *(const short8*)(ar + kb*32);
        short8 bb = (kb < 4) ? Ch[kb] : ((kb < 8) ? Cl[kb-4] : Ch[kb-8]);
        d = __builtin_amdgcn_mfma_f32_16x16x32_bf16(a, bb, d, 0, 0, 0);
      }
      float partial = 0.f;
      #pragma unroll
      for(int r = 0; r < 4; ++r){
        int o = wv*16 + quad*4 + r;
        float h3 = leaky(d[r] + p.t[8][o]);
        partial = fmaf(p.W9[o], h3, partial);
      }
      partial += __shfl_xor(partial, 16, 64);
      partial += __shfl_xor(partial, 32, 64);
      if(lane < 16) TMP[wv*16 + lane] = partial;
    }
    __syncthreads();
    if(tid < 16 && (n0 + tid) < NPT)
      p.out[(size_t)b*NPT + n0 + tid] = TMP[tid] + TMP[16 + tid];
    __syncthreads();
  }
}

extern "C" void kernel_launch(void* const* d_in, const int* in_sizes, int n_in,
                              void* d_out, int out_size, void* d_ws, size_t ws_size,
                              hipStream_t stream) {
  (void)n_in; (void)out_size; (void)ws_size;
  PrepP pp;
  for(int i = 0; i < 9; ++i) pp.W[i] = (const float*)d_in[1 + i];
  for(int i = 0; i < 9; ++i) pp.s[i] = (const float*)d_in[11 + 2*i];
  pp.ws = (float*)d_ws;
  prep_kernel<<<256, 256, 0, stream>>>(pp);

  MainP mp;
  mp.obs = (const float*)d_in[0];
  mp.W9  = (const float*)d_in[10];
  for(int i = 0; i < 9; ++i) mp.t[i] = (const float*)d_in[12 + 2*i];
  mp.ws  = (const float*)d_ws;
  mp.out = (float*)d_out;
  const int B = in_sizes[0] / 3000;
  dgcnn<<<B, 256, 0, stream>>>(mp);
}